// Round 15
// baseline (482.336 us; speedup 1.0000x reference)
//
#include <hip/hip_runtime.h>
#include <math.h>

#define M_PTS 8192
#define MK    131072   // M_PTS*16
// WORKSPACE: nidx 512KB @0, stats 8KB @524288 -> 532KB total (known-safe budget).

__device__ __forceinline__ float elu(float v){ return v > 0.f ? v : __expf(v)-1.0f; }

// Order-preserving u32 key of the np-exact distance; the ONE codegen for both phases:
// contract off, d2 staged in c.w, fma-chain dot, uncontracted (d2q+d2j)-(2*dot).
__device__ __forceinline__ unsigned distkey(float4 c, float qx, float qy, float qz, float d2q){
  #pragma clang fp contract(off)
  float dot  = __builtin_fmaf(c.z, qz, __builtin_fmaf(c.y, qy, __builtin_fmaf(c.x, qx, 0.0f)));
  float A    = d2q + c.w;
  float B    = 2.0f * dot;
  float dist = A - B;
  unsigned u = __float_as_uint(dist);
  return u ^ ((unsigned)((int)u >> 31) | 0x80000000u);
}

// ---------------- knn: one wave/query. Phase A: u32 min/max top-8 -> thr.
// Phase B: ballot-compacted collect of key<=thr, then exact u64 pop-min emit. No atomics.
__global__ __launch_bounds__(256) void knn_kernel(const float* __restrict__ pos,
                                                  int* __restrict__ nidx,
                                                  float* __restrict__ st){
  #pragma clang fp contract(off)
  __shared__ float4 cand[1024];
  __shared__ unsigned long long hits[4][64];
  int tid  = threadIdx.x;
  int lane = tid & 63;
  int wv   = tid >> 6;
  int q    = blockIdx.x*4 + wv;
  if (blockIdx.x == 0){
    for (int i = tid; i < 2048; i += 256) st[i] = 0.f;
  }
  float qx = pos[3*q], qy = pos[3*q+1], qz = pos[3*q+2];
  float d2q = (qx*qx + qy*qy) + qz*qz;   // np.sum(p*p,1) rounding, contract off

  // ---- phase A: per-lane sorted top-8 keys, u32 min/max bubble ----
  unsigned ka[8];
  #pragma unroll
  for (int s=0;s<8;s++) ka[s] = 0xFFFFFFFFu;

  for (int base = 0; base < M_PTS; base += 1024){
    {
      const float4* pv = (const float4*)(pos + (size_t)base*3);
      float4 f0 = pv[3*tid], f1 = pv[3*tid+1], f2 = pv[3*tid+2];
      cand[4*tid  ] = make_float4(f0.x,f0.y,f0.z,(f0.x*f0.x + f0.y*f0.y) + f0.z*f0.z);
      cand[4*tid+1] = make_float4(f0.w,f1.x,f1.y,(f0.w*f0.w + f1.x*f1.x) + f1.y*f1.y);
      cand[4*tid+2] = make_float4(f1.z,f1.w,f2.x,(f1.z*f1.z + f1.w*f1.w) + f2.x*f2.x);
      cand[4*tid+3] = make_float4(f2.y,f2.z,f2.w,(f2.y*f2.y + f2.z*f2.z) + f2.w*f2.w);
    }
    __syncthreads();
    #pragma unroll
    for (int k=0; k<16; k++){
      unsigned v = distkey(cand[lane + k*64], qx, qy, qz, d2q);
      #pragma unroll
      for (int s=0;s<8;s++){
        unsigned mn = min(v, ka[s]);
        unsigned mx = max(v, ka[s]);
        ka[s] = mn; v = mx;
      }
    }
    __syncthreads();
  }

  // ---- 16 pop-min rounds -> thr (>= true 16th-smallest key; tie-collapse only inflates) ----
  unsigned thr = 0xFFFFFFFFu;
  for (int r=0; r<16; r++){
    unsigned mine = ka[0];
    unsigned best = mine;
    #pragma unroll
    for (int off=32; off>0; off>>=1){
      unsigned o = __shfl_xor(best, off, 64);
      best = min(best, o);
    }
    bool adv = (best == mine);
    #pragma unroll
    for (int s=0;s<7;s++) ka[s] = adv ? ka[s+1] : ka[s];
    ka[7] = adv ? 0xFFFFFFFFu : ka[7];
    thr = best;
  }

  // ---- phase B: collect key<=thr via ballot compaction (wave-uniform cnt, no atomics) ----
  int cnt = 0;
  for (int base = 0; base < M_PTS; base += 1024){
    {
      const float4* pv = (const float4*)(pos + (size_t)base*3);
      float4 f0 = pv[3*tid], f1 = pv[3*tid+1], f2 = pv[3*tid+2];
      cand[4*tid  ] = make_float4(f0.x,f0.y,f0.z,(f0.x*f0.x + f0.y*f0.y) + f0.z*f0.z);
      cand[4*tid+1] = make_float4(f0.w,f1.x,f1.y,(f0.w*f0.w + f1.x*f1.x) + f1.y*f1.y);
      cand[4*tid+2] = make_float4(f1.z,f1.w,f2.x,(f1.z*f1.z + f1.w*f1.w) + f2.x*f2.x);
      cand[4*tid+3] = make_float4(f2.y,f2.z,f2.w,(f2.y*f2.y + f2.z*f2.z) + f2.w*f2.w);
    }
    __syncthreads();
    #pragma unroll
    for (int k=0; k<16; k++){
      int j = base + lane + k*64;
      unsigned u = distkey(cand[lane + k*64], qx, qy, qz, d2q);
      bool hit = (u <= thr);
      unsigned long long m = __ballot(hit);
      if (hit){
        int slot = cnt + __popcll(m & ((1ull<<lane)-1ull));
        if (slot < 64) hits[wv][slot] = ((unsigned long long)u << 32) | (unsigned)j;
      }
      cnt += (int)__popcll(m);
    }
    __syncthreads();
  }

  // ---- exact emit: 16 rounds of u64 pop-min over the hit list (keys unique via j) ----
  int cc = min(cnt, 64);
  unsigned long long mine = (lane < cc) ? hits[wv][lane] : ~0ull;
  for (int r=0; r<16; r++){
    unsigned long long best = mine;
    #pragma unroll
    for (int off=32; off>0; off>>=1){
      unsigned long long o = __shfl_xor(best, off, 64);
      best = (o < best) ? o : best;
    }
    if (mine == best) mine = ~0ull;
    if (lane == 0) nidx[q*16 + r] = (int)(unsigned)best;
  }
}

// 4-row helpers for the t-chain stats (double the block count for occupancy)
#define COMPUTE_RELF_4()                                              \
  for (int f = tid; f < 4*48; f += 256){                              \
    int p = f/48, kd = f%48, k = kd/3, d = kd%3;                      \
    int j = nidx[(m0+p)*16 + k];                                      \
    relf[p][kd] = pos[3*j+d] - pos[3*(m0+p)+d];                       \
  }                                                                   \
  __syncthreads();

#define COMPUTE_T1_4(acc)                                             \
  _Pragma("unroll")                                                   \
  for (int p=0;p<4;p++) acc[p] = b2[tid];                             \
  for (int kk=0; kk<48; kk+=4){                                       \
    float w0v = w2[kk*256+tid],     w1v = w2[(kk+1)*256+tid];         \
    float w2v = w2[(kk+2)*256+tid], w3v = w2[(kk+3)*256+tid];         \
    _Pragma("unroll")                                                 \
    for (int p=0;p<4;p++){                                            \
      float4 r4 = *(const float4*)&relf[p][kk];                       \
      acc[p] += r4.x*w0v + r4.y*w1v + r4.z*w2v + r4.w*w3v;            \
    }                                                                 \
  }

// ---------------- stats_a: blocks [0,512) -> s1 (h1 stats); [512,2560) -> s3 (t1 stats, 4 rows) ----------------
__global__ __launch_bounds__(256) void stats_a_kernel(const float* __restrict__ pos,
    const int* __restrict__ nidx,
    const float* __restrict__ w1a, const float* __restrict__ b1a,
    const float* __restrict__ w2,  const float* __restrict__ b2,
    float* __restrict__ s1, float* __restrict__ s3){
  int tid = threadIdx.x;
  if (blockIdx.x < 512){
    __shared__ float relS[256][3];
    __shared__ float red[8][64];
    int r = blockIdx.x*256 + tid;
    int m = r >> 4;
    int j = nidx[r];
    relS[tid][0] = pos[3*j  ]-pos[3*m  ];
    relS[tid][1] = pos[3*j+1]-pos[3*m+1];
    relS[tid][2] = pos[3*j+2]-pos[3*m+2];
    __syncthreads();
    int c = tid & 31, g = tid >> 5;
    float w0=w1a[c], w1v=w1a[32+c], w2v=w1a[64+c], b=b1a[c];
    float s=0.f, q=0.f;
    for (int rr=g*32; rr<g*32+32; rr++){
      float h = elu(b + relS[rr][0]*w0 + relS[rr][1]*w1v + relS[rr][2]*w2v);
      s += h; q += h*h;
    }
    red[g][c]=s; red[g][32+c]=q;
    __syncthreads();
    if (tid < 64){
      float a=0.f;
      #pragma unroll
      for (int gg=0;gg<8;gg++) a += red[gg][tid];
      atomicAdd(&s1[tid], a);
    }
  } else {
    __shared__ float relf[4][48];
    int m0 = (blockIdx.x-512)*4;
    COMPUTE_RELF_4();
    float acc[4];
    COMPUTE_T1_4(acc);
    float s=0.f, q=0.f;
    #pragma unroll
    for (int p=0;p<4;p++){ float v = elu(acc[p]); s += v; q += v*v; }
    atomicAdd(&s3[tid], s); atomicAdd(&s3[256+tid], q);
  }
}

// ---------------- stats_b: blocks [0,2048) -> s2 (h2 stats); [2048,4096) -> s4 (t2 stats, 4 rows) ----------------
__global__ __launch_bounds__(256) void stats_b_kernel(const float* __restrict__ pos,
    const int* __restrict__ nidx,
    const float* __restrict__ w1a, const float* __restrict__ b1a,
    const float* __restrict__ s1,  const float* __restrict__ g1a, const float* __restrict__ be1a,
    const float* __restrict__ w1b, const float* __restrict__ b1b,
    const float* __restrict__ w2,  const float* __restrict__ b2,
    const float* __restrict__ s3,  const float* __restrict__ g2a, const float* __restrict__ be2a,
    const float* __restrict__ wc2a,const float* __restrict__ bc2a,
    float* __restrict__ s2, float* __restrict__ s4){
  int tid = threadIdx.x;
  const float invMK = 1.f/(float)MK;
  const float invM  = 1.f/8192.f;
  if (blockIdx.x < 2048){
    __shared__ float xnS[64][33];
    __shared__ float red[8][64];
    __shared__ float muA[32], ivA[32];
    if (tid < 32){
      float mu  = s1[tid]*invMK;
      float var = s1[32+tid]*invMK - mu*mu;
      muA[tid] = mu; ivA[tid] = rsqrtf(var+1e-5f)*g1a[tid];
    }
    __syncthreads();
    {
      int rl = tid >> 2;
      int r  = blockIdx.x*64 + rl;
      int m = r >> 4;
      int j = nidx[r];
      float rx = pos[3*j]-pos[3*m], ry = pos[3*j+1]-pos[3*m+1], rz = pos[3*j+2]-pos[3*m+2];
      int c0 = (tid & 3)*8;
      #pragma unroll
      for (int u=0; u<8; u++){
        int cc = c0 + u;
        float h = elu(b1a[cc] + rx*w1a[cc] + ry*w1a[32+cc] + rz*w1a[64+cc]);
        xnS[rl][cc] = (h-muA[cc])*ivA[cc] + be1a[cc];
      }
    }
    __syncthreads();
    int o = tid & 31, g = tid >> 5;
    float wcol[32];
    #pragma unroll
    for (int cc=0;cc<32;cc++) wcol[cc] = w1b[cc*32+o];
    float bo = b1b[o], s=0.f, q=0.f;
    for (int rr=g*8; rr<g*8+8; rr++){
      float a = bo;
      #pragma unroll
      for (int cc=0;cc<32;cc++) a += xnS[rr][cc]*wcol[cc];
      float v = elu(a);
      s += v; q += v*v;
    }
    red[g][o]=s; red[g][32+o]=q;
    __syncthreads();
    if (tid < 64){
      float a=0.f;
      #pragma unroll
      for (int gg=0;gg<8;gg++) a += red[gg][tid];
      atomicAdd(&s2[tid], a);
    }
  } else {
    __shared__ float relf[4][48];
    __shared__ float tn[4][256];
    int m0 = (blockIdx.x-2048)*4;
    COMPUTE_RELF_4();
    float acc[4];
    COMPUTE_T1_4(acc);
    float mu3  = s3[tid]*invM;
    float var3 = s3[256+tid]*invM - mu3*mu3;
    float i3   = rsqrtf(var3+1e-5f)*g2a[tid];
    float bb3  = be2a[tid];
    #pragma unroll
    for (int p=0;p<4;p++) tn[p][tid] = (elu(acc[p])-mu3)*i3 + bb3;
    __syncthreads();
    int c = tid >> 4;
    float wreg[16];
    const float4* wv4 = (const float4*)(wc2a + tid*16);
    #pragma unroll
    for (int v=0; v<4; v++){ float4 f = wv4[v]; wreg[4*v]=f.x; wreg[4*v+1]=f.y; wreg[4*v+2]=f.z; wreg[4*v+3]=f.w; }
    float bias = bc2a[tid];
    float s=0.f, q=0.f;
    #pragma unroll
    for (int p=0;p<4;p++){
      float a2 = bias;
      #pragma unroll
      for (int l=0;l<16;l++) a2 += tn[p][c*16+l]*wreg[l];
      float v = elu(a2);
      s += v; q += v*v;
    }
    atomicAdd(&s4[tid], s); atomicAdd(&s4[256+tid], q);
  }
}

// ---------------- s5 = stats of t3 (no elu), 4 rows/block ----------------
__global__ __launch_bounds__(256) void t3_stats_kernel(const float* __restrict__ pos,
    const int* __restrict__ nidx, const float* __restrict__ w2, const float* __restrict__ b2,
    const float* __restrict__ s3, const float* __restrict__ g2a, const float* __restrict__ be2a,
    const float* __restrict__ wc2a, const float* __restrict__ bc2a,
    const float* __restrict__ s4, const float* __restrict__ g2b, const float* __restrict__ be2b,
    const float* __restrict__ wc2b, const float* __restrict__ bc2b, float* __restrict__ s5){
  __shared__ float relf[4][48];
  __shared__ float tn[4][256];
  __shared__ float tn2[4][256];
  int m0 = blockIdx.x*4, tid = threadIdx.x;
  const float invM = 1.f/8192.f;
  COMPUTE_RELF_4();
  float acc[4];
  COMPUTE_T1_4(acc);
  float mu3  = s3[tid]*invM;
  float var3 = s3[256+tid]*invM - mu3*mu3;
  float i3   = rsqrtf(var3+1e-5f)*g2a[tid];
  float bb3  = be2a[tid];
  #pragma unroll
  for (int p=0;p<4;p++) tn[p][tid] = (elu(acc[p])-mu3)*i3 + bb3;
  __syncthreads();
  int c = tid >> 4;
  float wreg[16];
  { const float4* wv4 = (const float4*)(wc2a + tid*16);
    #pragma unroll
    for (int v=0; v<4; v++){ float4 f = wv4[v]; wreg[4*v]=f.x; wreg[4*v+1]=f.y; wreg[4*v+2]=f.z; wreg[4*v+3]=f.w; } }
  float bias = bc2a[tid];
  float mu4  = s4[tid]*invM;
  float var4 = s4[256+tid]*invM - mu4*mu4;
  float i4   = rsqrtf(var4+1e-5f)*g2b[tid];
  float bb4  = be2b[tid];
  float t2v[4];
  #pragma unroll
  for (int p=0;p<4;p++){
    float a2 = bias;
    #pragma unroll
    for (int l=0;l<16;l++) a2 += tn[p][c*16+l]*wreg[l];
    t2v[p] = elu(a2);
  }
  #pragma unroll
  for (int p=0;p<4;p++) tn2[p][tid] = (t2v[p]-mu4)*i4 + bb4;
  __syncthreads();
  float w2reg[16];
  { const float4* wv4 = (const float4*)(wc2b + tid*16);
    #pragma unroll
    for (int v=0; v<4; v++){ float4 f = wv4[v]; w2reg[4*v]=f.x; w2reg[4*v+1]=f.y; w2reg[4*v+2]=f.z; w2reg[4*v+3]=f.w; } }
  float bias2 = bc2b[tid];
  float s=0.f, q=0.f;
  #pragma unroll
  for (int p=0;p<4;p++){
    float a3 = bias2;
    #pragma unroll
    for (int l=0;l<16;l++) a3 += tn2[p][c*16+l]*w2reg[l];
    s += a3; q += a3*a3;
  }
  atomicAdd(&s5[tid], s); atomicAdd(&s5[256+tid], q);
}

// ---------------- final: recompute t-chain + h2, X-transform, depthwise, linear ----------------
#define PF 4
__global__ __launch_bounds__(256) void final_kernel(
    const float* __restrict__ x, const float* __restrict__ pos, const int* __restrict__ nidx,
    const float* __restrict__ w1a, const float* __restrict__ b1a,
    const float* __restrict__ g1a, const float* __restrict__ be1a,
    const float* __restrict__ w1b, const float* __restrict__ b1b,
    const float* __restrict__ g1b, const float* __restrict__ be1b,
    const float* __restrict__ w2,  const float* __restrict__ b2,
    const float* __restrict__ g2a, const float* __restrict__ be2a,
    const float* __restrict__ wc2a,const float* __restrict__ bc2a,
    const float* __restrict__ g2b, const float* __restrict__ be2b,
    const float* __restrict__ wc2b,const float* __restrict__ bc2b,
    const float* __restrict__ g2c, const float* __restrict__ be2c,
    const float* __restrict__ wcd, const float* __restrict__ bcd,
    const float* __restrict__ wl,  const float* __restrict__ bl,
    const float* __restrict__ st,
    float* __restrict__ out){
  __shared__ float relf[PF][48];
  __shared__ float tA[PF][256];
  __shared__ float tB[PF][256];
  __shared__ float xs[PF*32*17];
  __shared__ float yy[PF][320];
  __shared__ int   sidx[PF*16];
  __shared__ float mu1[32], i1g[32], mu2[32], i2g[32];
  int tid = threadIdx.x;
  int m0  = blockIdx.x*PF;
  const float invMK = 1.f/(float)MK;
  const float invM  = 1.f/8192.f;

  if (tid < PF*16) sidx[tid] = nidx[m0*16 + tid];
  for (int f = tid; f < PF*48; f += 256){
    int p = f/48, kd = f%48, k = kd/3, d = kd%3;
    int j = nidx[(m0+p)*16 + k];
    relf[p][kd] = pos[3*j+d] - pos[3*(m0+p)+d];
  }
  if (tid < 32){
    float mu  = st[tid]*invMK;
    float var = st[32+tid]*invMK - mu*mu;
    mu1[tid] = mu; i1g[tid] = rsqrtf(var+1e-5f)*g1a[tid];
    float mu_2  = st[64+tid]*invMK;
    float var_2 = st[96+tid]*invMK - mu_2*mu_2;
    mu2[tid] = mu_2; i2g[tid] = rsqrtf(var_2+1e-5f)*g1b[tid];
  }
  float mu3 = st[128+tid]*invM, var3 = st[384+tid]*invM - mu3*mu3;
  float i3 = rsqrtf(var3+1e-5f)*g2a[tid], bb3 = be2a[tid];
  float mu4 = st[640+tid]*invM, var4 = st[896+tid]*invM - mu4*mu4;
  float i4 = rsqrtf(var4+1e-5f)*g2b[tid], bb4 = be2b[tid];
  float mu5 = st[1152+tid]*invM, var5 = st[1408+tid]*invM - mu5*mu5;
  float i5 = rsqrtf(var5+1e-5f)*g2c[tid], bb5 = be2c[tid];
  __syncthreads();

  {
    float a[PF];
    #pragma unroll
    for (int p=0;p<PF;p++) a[p] = b2[tid];
    for (int kk=0; kk<48; kk+=4){
      float w0v = w2[kk*256 + tid],     w1v = w2[(kk+1)*256 + tid];
      float w2v = w2[(kk+2)*256 + tid], w3v = w2[(kk+3)*256 + tid];
      #pragma unroll
      for (int p=0;p<PF;p++){
        float4 r4 = *(const float4*)&relf[p][kk];
        a[p] += r4.x*w0v + r4.y*w1v + r4.z*w2v + r4.w*w3v;
      }
    }
    #pragma unroll
    for (int p=0;p<PF;p++) tA[p][tid] = (elu(a[p])-mu3)*i3 + bb3;
  }
  __syncthreads();

  int c = tid >> 4;
  {
    float wreg[16];
    const float4* wv4 = (const float4*)(wc2a + tid*16);
    #pragma unroll
    for (int v=0; v<4; v++){ float4 f = wv4[v]; wreg[4*v]=f.x; wreg[4*v+1]=f.y; wreg[4*v+2]=f.z; wreg[4*v+3]=f.w; }
    float bias = bc2a[tid];
    float t2v[PF];
    #pragma unroll
    for (int p=0;p<PF;p++){
      float a2 = bias;
      #pragma unroll
      for (int l=0;l<16;l++) a2 += tA[p][c*16+l]*wreg[l];
      t2v[p] = elu(a2);
    }
    #pragma unroll
    for (int p=0;p<PF;p++) tB[p][tid] = (t2v[p]-mu4)*i4 + bb4;
  }
  __syncthreads();

  {
    float w2reg[16];
    const float4* wv4 = (const float4*)(wc2b + tid*16);
    #pragma unroll
    for (int v=0; v<4; v++){ float4 f = wv4[v]; w2reg[4*v]=f.x; w2reg[4*v+1]=f.y; w2reg[4*v+2]=f.z; w2reg[4*v+3]=f.w; }
    float bias2 = bc2b[tid];
    #pragma unroll
    for (int p=0;p<PF;p++){
      float a3 = bias2;
      #pragma unroll
      for (int l=0;l<16;l++) a3 += tB[p][c*16+l]*w2reg[l];
      tA[p][tid] = (a3-mu5)*i5 + bb5;
    }
  }

  {
    int row = tid >> 2;
    int p = row >> 4, k = row & 15;
    int q8 = (tid & 3)*8;
    int m = m0 + p;
    int j = sidx[p*16 + k];
    float rx = pos[3*j]-pos[3*m], ry = pos[3*j+1]-pos[3*m+1], rz = pos[3*j+2]-pos[3*m+2];
    float xn[32];
    #pragma unroll
    for (int cc=0; cc<32; cc+=4){
      float4 wa = *(const float4*)&w1a[cc];
      float4 wb = *(const float4*)&w1a[32+cc];
      float4 wc = *(const float4*)&w1a[64+cc];
      float4 ba = *(const float4*)&b1a[cc];
      float4 mm = *(const float4*)&mu1[cc];
      float4 ii = *(const float4*)&i1g[cc];
      float4 be = *(const float4*)&be1a[cc];
      xn[cc  ] = (elu(ba.x + rx*wa.x + ry*wb.x + rz*wc.x) - mm.x)*ii.x + be.x;
      xn[cc+1] = (elu(ba.y + rx*wa.y + ry*wb.y + rz*wc.y) - mm.y)*ii.y + be.y;
      xn[cc+2] = (elu(ba.z + rx*wa.z + ry*wb.z + rz*wc.z) - mm.z)*ii.z + be.z;
      xn[cc+3] = (elu(ba.w + rx*wa.w + ry*wb.w + rz*wc.w) - mm.w)*ii.w + be.w;
    }
    float acc8[8];
    {
      float4 b0 = *(const float4*)&b1b[q8];
      float4 b1v = *(const float4*)&b1b[q8+4];
      acc8[0]=b0.x; acc8[1]=b0.y; acc8[2]=b0.z; acc8[3]=b0.w;
      acc8[4]=b1v.x; acc8[5]=b1v.y; acc8[6]=b1v.z; acc8[7]=b1v.w;
    }
    #pragma unroll
    for (int cc=0; cc<32; cc++){
      float xv = xn[cc];
      float4 wr0 = *(const float4*)&w1b[cc*32+q8];
      float4 wr1 = *(const float4*)&w1b[cc*32+q8+4];
      acc8[0]+=xv*wr0.x; acc8[1]+=xv*wr0.y; acc8[2]+=xv*wr0.z; acc8[3]+=xv*wr0.w;
      acc8[4]+=xv*wr1.x; acc8[5]+=xv*wr1.y; acc8[6]+=xv*wr1.z; acc8[7]+=xv*wr1.w;
    }
    #pragma unroll
    for (int oo=0; oo<8; oo++){
      int o = q8 + oo;
      float h2v = elu(acc8[oo]);
      xs[(p*32 + o)*17 + k] = (h2v-mu2[o])*i2g[o] + be1b[o];
    }
  }
  __syncthreads();

  for (int pair = tid; pair < PF*160; pair += 256){
    int p = pair / 160, cch = pair % 160;
    float av[16];
    if (cch < 32){
      #pragma unroll
      for (int k16=0;k16<16;k16++) av[k16] = xs[(p*32+cch)*17 + k16];
    } else {
      #pragma unroll
      for (int k16=0;k16<16;k16++) av[k16] = x[(size_t)sidx[p*16+k16]*128 + (cch-32)];
    }
    float xt[16];
    #pragma unroll
    for (int j16=0;j16<16;j16++) xt[j16]=0.f;
    #pragma unroll
    for (int k16=0;k16<16;k16++){
      float a = av[k16];
      #pragma unroll
      for (int j16=0;j16<16;j16++) xt[j16] += a*tA[p][k16*16+j16];
    }
    float y0 = bcd[cch*2], y1 = bcd[cch*2+1];
    #pragma unroll
    for (int l=0;l<16;l++){
      y0 += xt[l]*wcd[cch*32 + l];
      y1 += xt[l]*wcd[cch*32 + 16 + l];
    }
    yy[p][cch*2] = y0; yy[p][cch*2+1] = y1;
  }
  __syncthreads();

  float accO[PF];
  #pragma unroll
  for (int p=0;p<PF;p++) accO[p] = bl[tid];
  for (int q=0; q<320; q+=4){
    float w0v = wl[q*256 + tid],     w1v = wl[(q+1)*256 + tid];
    float w2v = wl[(q+2)*256 + tid], w3v = wl[(q+3)*256 + tid];
    #pragma unroll
    for (int p=0;p<PF;p++){
      float4 y4 = *(const float4*)&yy[p][q];
      accO[p] += y4.x*w0v + y4.y*w1v + y4.z*w2v + y4.w*w3v;
    }
  }
  #pragma unroll
  for (int p=0;p<PF;p++) out[(size_t)(m0+p)*256 + tid] = accO[p];
}

extern "C" void kernel_launch(void* const* d_in, const int* in_sizes, int n_in,
                              void* d_out, int out_size, void* d_ws, size_t ws_size,
                              hipStream_t stream){
  const float* x    = (const float*)d_in[0];
  const float* pos  = (const float*)d_in[1];
  const float* w1a  = (const float*)d_in[2];
  const float* b1a  = (const float*)d_in[3];
  const float* g1a  = (const float*)d_in[4];
  const float* be1a = (const float*)d_in[5];
  const float* w1b  = (const float*)d_in[6];
  const float* b1b  = (const float*)d_in[7];
  const float* g1b  = (const float*)d_in[8];
  const float* be1b = (const float*)d_in[9];
  const float* w2   = (const float*)d_in[10];
  const float* b2   = (const float*)d_in[11];
  const float* g2a  = (const float*)d_in[12];
  const float* be2a = (const float*)d_in[13];
  const float* wc2a = (const float*)d_in[14];
  const float* bc2a = (const float*)d_in[15];
  const float* g2b  = (const float*)d_in[16];
  const float* be2b = (const float*)d_in[17];
  const float* wc2b = (const float*)d_in[18];
  const float* bc2b = (const float*)d_in[19];
  const float* g2c  = (const float*)d_in[20];
  const float* be2c = (const float*)d_in[21];
  const float* wcd  = (const float*)d_in[22];
  const float* bcd  = (const float*)d_in[23];
  const float* wl   = (const float*)d_in[24];
  const float* bl   = (const float*)d_in[25];
  float* out = (float*)d_out;

  char* ws = (char*)d_ws;
  int*   nidx = (int*)(ws + 0);          // 512 KB
  float* st   = (float*)(ws + 524288);   // 8 KB (s1@0, s2@64, s3@128, s4@640, s5@1152)
  float* s1 = st;
  float* s2 = st + 64;
  float* s3 = st + 128;
  float* s4 = st + 640;
  float* s5 = st + 1152;

  knn_kernel<<<2048,256,0,stream>>>(pos, nidx, st);
  stats_a_kernel<<<2560,256,0,stream>>>(pos, nidx, w1a, b1a, w2, b2, s1, s3);
  stats_b_kernel<<<4096,256,0,stream>>>(pos, nidx, w1a, b1a, s1, g1a, be1a, w1b, b1b,
                                        w2, b2, s3, g2a, be2a, wc2a, bc2a, s2, s4);
  t3_stats_kernel<<<2048,256,0,stream>>>(pos, nidx, w2, b2, s3, g2a, be2a, wc2a, bc2a,
                                         s4, g2b, be2b, wc2b, bc2b, s5);
  final_kernel<<<2048,256,0,stream>>>(x, pos, nidx,
                                      w1a, b1a, g1a, be1a, w1b, b1b, g1b, be1b,
                                      w2, b2, g2a, be2a, wc2a, bc2a,
                                      g2b, be2b, wc2b, bc2b, g2c, be2c,
                                      wcd, bcd, wl, bl, st, out);
}

// Round 17
// 389.430 us; speedup vs baseline: 1.2386x; 1.2386x over previous
//
#include <hip/hip_runtime.h>
#include <math.h>

#define M_PTS 8192
#define MK    131072   // M_PTS*16
// WORKSPACE: nidx 512KB @0, stats 8KB @524288 -> 532KB (known-safe).
// d_out (8192x256 f32 = 8MB) doubles as t-chain scratch: t1act -> t2act -> t3 -> final output.

__device__ __forceinline__ float elu(float v){ return v > 0.f ? v : __expf(v)-1.0f; }

__device__ __forceinline__ unsigned distkey(float4 c, float qx, float qy, float qz, float d2q){
  #pragma clang fp contract(off)
  float dot  = __builtin_fmaf(c.z, qz, __builtin_fmaf(c.y, qy, __builtin_fmaf(c.x, qx, 0.0f)));
  float A    = d2q + c.w;
  float B    = 2.0f * dot;
  float dist = A - B;
  unsigned u = __float_as_uint(dist);
  return u ^ ((unsigned)((int)u >> 31) | 0x80000000u);
}

// ---------------- knn (verbatim R14: two-phase, ballot compaction, no atomics) ----------------
__global__ __launch_bounds__(256) void knn_kernel(const float* __restrict__ pos,
                                                  int* __restrict__ nidx,
                                                  float* __restrict__ st){
  #pragma clang fp contract(off)
  __shared__ float4 cand[1024];
  __shared__ unsigned long long hits[4][64];
  int tid  = threadIdx.x;
  int lane = tid & 63;
  int wv   = tid >> 6;
  int q    = blockIdx.x*4 + wv;
  if (blockIdx.x == 0){
    for (int i = tid; i < 2048; i += 256) st[i] = 0.f;
  }
  float qx = pos[3*q], qy = pos[3*q+1], qz = pos[3*q+2];
  float d2q = (qx*qx + qy*qy) + qz*qz;

  unsigned ka[8];
  #pragma unroll
  for (int s=0;s<8;s++) ka[s] = 0xFFFFFFFFu;

  for (int base = 0; base < M_PTS; base += 1024){
    for (int t = tid; t < 1024; t += 256){
      int j = base + t;
      float x = pos[3*j], y = pos[3*j+1], z = pos[3*j+2];
      float d2v = (x*x + y*y) + z*z;
      cand[t] = make_float4(x,y,z,d2v);
    }
    __syncthreads();
    #pragma unroll
    for (int k=0; k<16; k++){
      unsigned v = distkey(cand[lane + k*64], qx, qy, qz, d2q);
      #pragma unroll
      for (int s=0;s<8;s++){
        unsigned mn = min(v, ka[s]);
        unsigned mx = max(v, ka[s]);
        ka[s] = mn; v = mx;
      }
    }
    __syncthreads();
  }

  unsigned thr = 0xFFFFFFFFu;
  for (int r=0; r<16; r++){
    unsigned mine = ka[0];
    unsigned best = mine;
    #pragma unroll
    for (int off=32; off>0; off>>=1){
      unsigned o = __shfl_xor(best, off, 64);
      best = min(best, o);
    }
    bool adv = (best == mine);
    #pragma unroll
    for (int s=0;s<7;s++) ka[s] = adv ? ka[s+1] : ka[s];
    ka[7] = adv ? 0xFFFFFFFFu : ka[7];
    thr = best;
  }

  int cnt = 0;
  for (int base = 0; base < M_PTS; base += 1024){
    for (int t = tid; t < 1024; t += 256){
      int j = base + t;
      float x = pos[3*j], y = pos[3*j+1], z = pos[3*j+2];
      float d2v = (x*x + y*y) + z*z;
      cand[t] = make_float4(x,y,z,d2v);
    }
    __syncthreads();
    #pragma unroll
    for (int k=0; k<16; k++){
      int j = base + lane + k*64;
      unsigned u = distkey(cand[lane + k*64], qx, qy, qz, d2q);
      bool hit = (u <= thr);
      unsigned long long m = __ballot(hit);
      if (hit){
        int slot = cnt + __popcll(m & ((1ull<<lane)-1ull));
        if (slot < 64) hits[wv][slot] = ((unsigned long long)u << 32) | (unsigned)j;
      }
      cnt += (int)__popcll(m);
    }
    __syncthreads();
  }

  int cc = min(cnt, 64);
  unsigned long long mine = (lane < cc) ? hits[wv][lane] : ~0ull;
  for (int r=0; r<16; r++){
    unsigned long long best = mine;
    #pragma unroll
    for (int off=32; off>0; off>>=1){
      unsigned long long o = __shfl_xor(best, off, 64);
      best = (o < best) ? o : best;
    }
    if (mine == best) mine = ~0ull;
    if (lane == 0) nidx[q*16 + r] = (int)(unsigned)best;
  }
}

#define COMPUTE_RELF_8()                                              \
  for (int f = tid; f < 8*48; f += 256){                              \
    int p = f/48, kd = f%48, k = kd/3, d = kd%3;                      \
    int j = nidx[(m0+p)*16 + k];                                      \
    relf[p][kd] = pos[3*j+d] - pos[3*(m0+p)+d];                       \
  }                                                                   \
  __syncthreads();

#define COMPUTE_T1_8(acc)                                             \
  _Pragma("unroll")                                                   \
  for (int p=0;p<8;p++) acc[p] = b2[tid];                             \
  for (int kk=0; kk<48; kk++){                                        \
    float w = w2[kk*256 + tid];                                       \
    _Pragma("unroll")                                                 \
    for (int p=0;p<8;p++) acc[p] += relf[p][kk]*w;                    \
  }

// ---------------- stats_a: [0,512) s1 (h1 stats); [512,1536) t1act -> d_out + s3 ----------------
__global__ __launch_bounds__(256) void stats_a_kernel(const float* __restrict__ pos,
    const int* __restrict__ nidx,
    const float* __restrict__ w1a, const float* __restrict__ b1a,
    const float* __restrict__ w2,  const float* __restrict__ b2,
    float* __restrict__ tact,
    float* __restrict__ s1, float* __restrict__ s3){
  int tid = threadIdx.x;
  if (blockIdx.x < 512){
    __shared__ float relS[256][3];
    __shared__ float red[8][64];
    int r = blockIdx.x*256 + tid;
    int m = r >> 4;
    int j = nidx[r];
    relS[tid][0] = pos[3*j  ]-pos[3*m  ];
    relS[tid][1] = pos[3*j+1]-pos[3*m+1];
    relS[tid][2] = pos[3*j+2]-pos[3*m+2];
    __syncthreads();
    int c = tid & 31, g = tid >> 5;
    float w0=w1a[c], w1v=w1a[32+c], w2v=w1a[64+c], b=b1a[c];
    float s=0.f, q=0.f;
    for (int rr=g*32; rr<g*32+32; rr++){
      float h = elu(b + relS[rr][0]*w0 + relS[rr][1]*w1v + relS[rr][2]*w2v);
      s += h; q += h*h;
    }
    red[g][c]=s; red[g][32+c]=q;
    __syncthreads();
    if (tid < 64){
      float a=0.f;
      #pragma unroll
      for (int gg=0;gg<8;gg++) a += red[gg][tid];
      atomicAdd(&s1[tid], a);
    }
  } else {
    __shared__ float relf[8][48];
    int m0 = (blockIdx.x-512)*8;
    COMPUTE_RELF_8();
    float acc[8];
    COMPUTE_T1_8(acc);
    float s=0.f, q=0.f;
    #pragma unroll
    for (int p=0;p<8;p++){
      float v = elu(acc[p]);
      s += v; q += v*v;
      tact[(size_t)(m0+p)*256 + tid] = v;
    }
    atomicAdd(&s3[tid], s); atomicAdd(&s3[256+tid], q);
  }
}

// ---------------- stats_b: [0,2048) s2 (h2 stats); [2048,3072) t2act = elu(gconv1(BN(t1act))) ----------------
__global__ __launch_bounds__(256) void stats_b_kernel(const float* __restrict__ pos,
    const int* __restrict__ nidx,
    const float* __restrict__ w1a, const float* __restrict__ b1a,
    const float* __restrict__ s1,  const float* __restrict__ g1a, const float* __restrict__ be1a,
    const float* __restrict__ w1b, const float* __restrict__ b1b,
    float* __restrict__ tact,
    const float* __restrict__ s3,  const float* __restrict__ g2a, const float* __restrict__ be2a,
    const float* __restrict__ wc2a,const float* __restrict__ bc2a,
    float* __restrict__ s2, float* __restrict__ s4){
  int tid = threadIdx.x;
  const float invMK = 1.f/(float)MK;
  const float invM  = 1.f/8192.f;
  if (blockIdx.x < 2048){
    __shared__ float xnS[64][33];
    __shared__ float red[8][64];
    __shared__ float muA[32], ivA[32];
    if (tid < 32){
      float mu  = s1[tid]*invMK;
      float var = s1[32+tid]*invMK - mu*mu;
      muA[tid] = mu; ivA[tid] = rsqrtf(var+1e-5f)*g1a[tid];
    }
    __syncthreads();
    {
      int rl = tid >> 2;
      int r  = blockIdx.x*64 + rl;
      int m = r >> 4;
      int j = nidx[r];
      float rx = pos[3*j]-pos[3*m], ry = pos[3*j+1]-pos[3*m+1], rz = pos[3*j+2]-pos[3*m+2];
      int c0 = (tid & 3)*8;
      #pragma unroll
      for (int u=0; u<8; u++){
        int cc = c0 + u;
        float h = elu(b1a[cc] + rx*w1a[cc] + ry*w1a[32+cc] + rz*w1a[64+cc]);
        xnS[rl][cc] = (h-muA[cc])*ivA[cc] + be1a[cc];
      }
    }
    __syncthreads();
    int o = tid & 31, g = tid >> 5;
    float wcol[32];
    #pragma unroll
    for (int cc=0;cc<32;cc++) wcol[cc] = w1b[cc*32+o];
    float bo = b1b[o], s=0.f, q=0.f;
    for (int rr=g*8; rr<g*8+8; rr++){
      float a = bo;
      #pragma unroll
      for (int cc=0;cc<32;cc++) a += xnS[rr][cc]*wcol[cc];
      float v = elu(a);
      s += v; q += v*v;
    }
    red[g][o]=s; red[g][32+o]=q;
    __syncthreads();
    if (tid < 64){
      float a=0.f;
      #pragma unroll
      for (int gg=0;gg<8;gg++) a += red[gg][tid];
      atomicAdd(&s2[tid], a);
    }
  } else {
    __shared__ float tn[8][256];
    int m0 = (blockIdx.x-2048)*8;
    float mu3  = s3[tid]*invM;
    float var3 = s3[256+tid]*invM - mu3*mu3;
    float i3   = rsqrtf(var3+1e-5f)*g2a[tid];
    float bb3  = be2a[tid];
    float tv[8];
    #pragma unroll
    for (int p=0;p<8;p++) tv[p] = tact[(size_t)(m0+p)*256 + tid];
    #pragma unroll
    for (int p=0;p<8;p++) tn[p][tid] = (tv[p]-mu3)*i3 + bb3;
    __syncthreads();
    int c = tid >> 4;
    float wreg[16];
    const float4* wv4 = (const float4*)(wc2a + tid*16);
    #pragma unroll
    for (int v=0; v<4; v++){ float4 f = wv4[v]; wreg[4*v]=f.x; wreg[4*v+1]=f.y; wreg[4*v+2]=f.z; wreg[4*v+3]=f.w; }
    float bias = bc2a[tid];
    float s=0.f, q=0.f;
    #pragma unroll
    for (int p=0;p<8;p++){
      float a2 = bias;
      #pragma unroll
      for (int l=0;l<16;l++) a2 += tn[p][c*16+l]*wreg[l];
      float v = elu(a2);
      s += v; q += v*v;
      tv[p] = v;
    }
    #pragma unroll
    for (int p=0;p<8;p++) tact[(size_t)(m0+p)*256 + tid] = tv[p];
    atomicAdd(&s4[tid], s); atomicAdd(&s4[256+tid], q);
  }
}

// ---------------- t3_stats: t3 = gconv2(BN(t2act)) (no elu) -> d_out + s5 ----------------
__global__ __launch_bounds__(256) void t3_stats_kernel(
    float* __restrict__ tact,
    const float* __restrict__ s4, const float* __restrict__ g2b, const float* __restrict__ be2b,
    const float* __restrict__ wc2b, const float* __restrict__ bc2b, float* __restrict__ s5){
  __shared__ float tn2[8][256];
  int m0 = blockIdx.x*8, tid = threadIdx.x;
  const float invM = 1.f/8192.f;
  float mu4  = s4[tid]*invM;
  float var4 = s4[256+tid]*invM - mu4*mu4;
  float i4   = rsqrtf(var4+1e-5f)*g2b[tid];
  float bb4  = be2b[tid];
  float tv[8];
  #pragma unroll
  for (int p=0;p<8;p++) tv[p] = tact[(size_t)(m0+p)*256 + tid];
  #pragma unroll
  for (int p=0;p<8;p++) tn2[p][tid] = (tv[p]-mu4)*i4 + bb4;
  __syncthreads();
  int c = tid >> 4;
  float w2reg[16];
  { const float4* wv4 = (const float4*)(wc2b + tid*16);
    #pragma unroll
    for (int v=0; v<4; v++){ float4 f = wv4[v]; w2reg[4*v]=f.x; w2reg[4*v+1]=f.y; w2reg[4*v+2]=f.z; w2reg[4*v+3]=f.w; } }
  float bias2 = bc2b[tid];
  float s=0.f, q=0.f;
  #pragma unroll
  for (int p=0;p<8;p++){
    float a3 = bias2;
    #pragma unroll
    for (int l=0;l<16;l++) a3 += tn2[p][c*16+l]*w2reg[l];
    s += a3; q += a3*a3;
    tv[p] = a3;
  }
  #pragma unroll
  for (int p=0;p<8;p++) tact[(size_t)(m0+p)*256 + tid] = tv[p];
  atomicAdd(&s5[tid], s); atomicAdd(&s5[256+tid], q);
}

// ---------------- final: read t3 from d_out, BN -> X-transform -> depthwise -> linear -> overwrite d_out ----------------
#define PF 4
__global__ __launch_bounds__(256) void final_kernel(
    const float* __restrict__ x, const float* __restrict__ pos, const int* __restrict__ nidx,
    const float* __restrict__ w1a, const float* __restrict__ b1a,
    const float* __restrict__ g1a, const float* __restrict__ be1a,
    const float* __restrict__ w1b, const float* __restrict__ b1b,
    const float* __restrict__ g1b, const float* __restrict__ be1b,
    const float* __restrict__ g2c, const float* __restrict__ be2c,
    const float* __restrict__ wcd, const float* __restrict__ bcd,
    const float* __restrict__ wl,  const float* __restrict__ bl,
    const float* __restrict__ st,
    float* __restrict__ out){
  __shared__ float tA[PF][256];
  __shared__ float xs[PF*32*17];
  __shared__ float yy[PF][320];
  __shared__ int   sidx[PF*16];
  __shared__ float mu1[32], i1g[32], mu2[32], i2g[32];
  int tid = threadIdx.x;
  int m0  = blockIdx.x*PF;
  const float invMK = 1.f/(float)MK;
  const float invM  = 1.f/8192.f;

  if (tid < PF*16) sidx[tid] = nidx[m0*16 + tid];
  if (tid < 32){
    float mu  = st[tid]*invMK;
    float var = st[32+tid]*invMK - mu*mu;
    mu1[tid] = mu; i1g[tid] = rsqrtf(var+1e-5f)*g1a[tid];
    float mu_2  = st[64+tid]*invMK;
    float var_2 = st[96+tid]*invMK - mu_2*mu_2;
    mu2[tid] = mu_2; i2g[tid] = rsqrtf(var_2+1e-5f)*g1b[tid];
  }
  // tt = BN(t3) straight from the cached t3 rows (this block's own rows of `out`)
  {
    float mu5 = st[1152+tid]*invM, var5 = st[1408+tid]*invM - mu5*mu5;
    float i5 = rsqrtf(var5+1e-5f)*g2c[tid], bb5 = be2c[tid];
    #pragma unroll
    for (int p=0;p<PF;p++){
      float v = out[(size_t)(m0+p)*256 + tid];
      tA[p][tid] = (v-mu5)*i5 + bb5;
    }
  }
  __syncthreads();

  {
    int row = tid >> 2;
    int p = row >> 4, k = row & 15;
    int q8 = (tid & 3)*8;
    int m = m0 + p;
    int j = sidx[p*16 + k];
    float rx = pos[3*j]-pos[3*m], ry = pos[3*j+1]-pos[3*m+1], rz = pos[3*j+2]-pos[3*m+2];
    float xn[32];
    #pragma unroll
    for (int cc=0; cc<32; cc++){
      float h = elu(b1a[cc] + rx*w1a[cc] + ry*w1a[32+cc] + rz*w1a[64+cc]);
      xn[cc] = (h-mu1[cc])*i1g[cc] + be1a[cc];
    }
    #pragma unroll
    for (int oo=0; oo<8; oo++){
      int o = q8 + oo;
      float a = b1b[o];
      #pragma unroll
      for (int cc=0; cc<32; cc++) a += xn[cc]*w1b[cc*32+o];
      float h2v = elu(a);
      xs[(p*32 + o)*17 + k] = (h2v-mu2[o])*i2g[o] + be1b[o];
    }
  }
  __syncthreads();

  for (int pair = tid; pair < PF*160; pair += 256){
    int p = pair / 160, cch = pair % 160;
    float av[16];
    if (cch < 32){
      #pragma unroll
      for (int k16=0;k16<16;k16++) av[k16] = xs[(p*32+cch)*17 + k16];
    } else {
      #pragma unroll
      for (int k16=0;k16<16;k16++) av[k16] = x[(size_t)sidx[p*16+k16]*128 + (cch-32)];
    }
    float xt[16];
    #pragma unroll
    for (int j16=0;j16<16;j16++) xt[j16]=0.f;
    #pragma unroll
    for (int k16=0;k16<16;k16++){
      float a = av[k16];
      #pragma unroll
      for (int j16=0;j16<16;j16++) xt[j16] += a*tA[p][k16*16+j16];
    }
    float y0 = bcd[cch*2], y1 = bcd[cch*2+1];
    #pragma unroll
    for (int l=0;l<16;l++){
      y0 += xt[l]*wcd[cch*32 + l];
      y1 += xt[l]*wcd[cch*32 + 16 + l];
    }
    yy[p][cch*2] = y0; yy[p][cch*2+1] = y1;
  }
  __syncthreads();

  float accO[PF];
  #pragma unroll
  for (int p=0;p<PF;p++) accO[p] = bl[tid];
  for (int q=0;q<320;q++){
    float w = wl[q*256 + tid];
    #pragma unroll
    for (int p=0;p<PF;p++) accO[p] += yy[p][q]*w;
  }
  #pragma unroll
  for (int p=0;p<PF;p++) out[(size_t)(m0+p)*256 + tid] = accO[p];
}

extern "C" void kernel_launch(void* const* d_in, const int* in_sizes, int n_in,
                              void* d_out, int out_size, void* d_ws, size_t ws_size,
                              hipStream_t stream){
  const float* x    = (const float*)d_in[0];
  const float* pos  = (const float*)d_in[1];
  const float* w1a  = (const float*)d_in[2];
  const float* b1a  = (const float*)d_in[3];
  const float* g1a  = (const float*)d_in[4];
  const float* be1a = (const float*)d_in[5];
  const float* w1b  = (const float*)d_in[6];
  const float* b1b  = (const float*)d_in[7];
  const float* g1b  = (const float*)d_in[8];
  const float* be1b = (const float*)d_in[9];
  const float* w2   = (const float*)d_in[10];
  const float* b2   = (const float*)d_in[11];
  const float* g2a  = (const float*)d_in[12];
  const float* be2a = (const float*)d_in[13];
  const float* wc2a = (const float*)d_in[14];
  const float* bc2a = (const float*)d_in[15];
  const float* g2b  = (const float*)d_in[16];
  const float* be2b = (const float*)d_in[17];
  const float* wc2b = (const float*)d_in[18];
  const float* bc2b = (const float*)d_in[19];
  const float* g2c  = (const float*)d_in[20];
  const float* be2c = (const float*)d_in[21];
  const float* wcd  = (const float*)d_in[22];
  const float* bcd  = (const float*)d_in[23];
  const float* wl   = (const float*)d_in[24];
  const float* bl   = (const float*)d_in[25];
  float* out = (float*)d_out;

  char* ws = (char*)d_ws;
  int*   nidx = (int*)(ws + 0);          // 512 KB
  float* st   = (float*)(ws + 524288);   // 8 KB (s1@0, s2@64, s3@128, s4@640, s5@1152)
  float* s1 = st;
  float* s2 = st + 64;
  float* s3 = st + 128;
  float* s4 = st + 640;
  float* s5 = st + 1152;

  knn_kernel<<<2048,256,0,stream>>>(pos, nidx, st);
  stats_a_kernel<<<1536,256,0,stream>>>(pos, nidx, w1a, b1a, w2, b2, out, s1, s3);
  stats_b_kernel<<<3072,256,0,stream>>>(pos, nidx, w1a, b1a, s1, g1a, be1a, w1b, b1b,
                                        out, s3, g2a, be2a, wc2a, bc2a, s2, s4);
  t3_stats_kernel<<<1024,256,0,stream>>>(out, s4, g2b, be2b, wc2b, bc2b, s5);
  final_kernel<<<2048,256,0,stream>>>(x, pos, nidx,
                                      w1a, b1a, g1a, be1a, w1b, b1b, g1b, be1b,
                                      g2c, be2c, wcd, bcd, wl, bl, st, out);
}